// Round 1
// baseline (517.444 us; speedup 1.0000x reference)
//
#include <hip/hip_runtime.h>
#include <math.h>

#define HID 1024
#define VOCAB 32000
#define LAYERS 4
#define MAXLEN 128
#define SPAN 2

// d_out layout (floats): logp [0,64000) | hidden_new [64000,68096) | attn_w [68096,68224)
#define OUT_LOGP 0
#define OUT_HID 64000
#define OUT_ATTNW 68096

// ws layout (floats)
#define WS_XCAT 0       // 3072: emb(2048) | attn_applied(1024)
#define WS_SCORES 3072  // 128
#define WS_X 3200       // 1024 (comb output)
#define WS_RED 4224     // 4: max0,max1,lse0,lse1
#define WS_LOGITS 8192  // 64000

// ---------- K1: attention scores + emb gather ----------
// grid 136 x 256. Blocks 0..127: score[b] = dot(attn_in, attn_W[b]) + attn_b[b]
// Blocks 128..135: copy emb (2048 floats) into ws xcat.
__global__ __launch_bounds__(256) void k_scores(const int* __restrict__ ids,
                                                const float* __restrict__ hidden,
                                                const float* __restrict__ embedding,
                                                const float* __restrict__ attn_W,
                                                const float* __restrict__ attn_b,
                                                float* __restrict__ ws) {
    int b = blockIdx.x;
    int t = threadIdx.x;
    if (b < MAXLEN) {
        const float4* W4 = (const float4*)(attn_W + (size_t)b * 3072);
        float sum = 0.f;
#pragma unroll
        for (int i = 0; i < 3; i++) {
            int k4 = t + 256 * i;            // 0..767
            float4 w = W4[k4];
            int e = k4 * 4;                  // element index base
            float4 x;
            if (e < 2048) {
                int row = ids[e >> 10];
                x = *(const float4*)(embedding + (size_t)row * HID + (e & 1023));
            } else {
                x = *(const float4*)(hidden + (e - 2048));  // hidden[0]
            }
            sum += w.x * x.x + w.y * x.y + w.z * x.z + w.w * x.w;
        }
        // block reduce (4 waves)
        __shared__ float sred[4];
        int lane = t & 63, wid = t >> 6;
        for (int o = 32; o > 0; o >>= 1) sum += __shfl_down(sum, o, 64);
        if (lane == 0) sred[wid] = sum;
        __syncthreads();
        if (t == 0) {
            float v = sred[0] + sred[1] + sred[2] + sred[3];
            ws[WS_SCORES + b] = v + attn_b[b];
        }
    } else {
        int idx = (b - MAXLEN) * 256 + t;    // 0..2047
        int row = ids[idx >> 10];
        ws[WS_XCAT + idx] = embedding[(size_t)row * HID + (idx & 1023)];
    }
}

// ---------- K2: softmax(128) + attn_applied ----------
// grid 8 x 128. Each block redundantly computes softmax, then 128 output cols.
__global__ __launch_bounds__(128) void k_softmax_apply(const float* __restrict__ enc,
                                                       float* __restrict__ ws,
                                                       float* __restrict__ out) {
    __shared__ float w[MAXLEN];
    __shared__ float red[2];
    int t = threadIdx.x;        // 0..127, two waves
    int lane = t & 63, wid = t >> 6;
    float s = ws[WS_SCORES + t];
    // max
    float m = s;
    for (int o = 32; o > 0; o >>= 1) m = fmaxf(m, __shfl_down(m, o, 64));
    if (lane == 0) red[wid] = m;
    __syncthreads();
    float gmax = fmaxf(red[0], red[1]);
    __syncthreads();
    // sum of exp
    float e = expf(s - gmax);
    float sum = e;
    for (int o = 32; o > 0; o >>= 1) sum += __shfl_down(sum, o, 64);
    if (lane == 0) red[wid] = sum;
    __syncthreads();
    float gsum = red[0] + red[1];
    float wt = e / gsum;
    w[t] = wt;
    if (blockIdx.x == 0) out[OUT_ATTNW + t] = wt;
    __syncthreads();
    // attn_applied[i] = sum_k w[k] * enc[k][i]
    int i = blockIdx.x * 128 + t;   // 0..1023
    float acc = 0.f;
#pragma unroll 8
    for (int k = 0; k < MAXLEN; k++) acc += w[k] * enc[(size_t)k * HID + i];
    ws[WS_XCAT + 2048 + i] = acc;
}

// ---------- K3: comb matvec + relu ----------
// grid 1024 x 256, block-per-row, dot over 3072.
__global__ __launch_bounds__(256) void k_comb(const float* __restrict__ comb_W,
                                              const float* __restrict__ comb_b,
                                              float* __restrict__ ws) {
    int r = blockIdx.x, t = threadIdx.x;
    const float4* W4 = (const float4*)(comb_W + (size_t)r * 3072);
    const float4* x4 = (const float4*)(ws + WS_XCAT);
    float sum = 0.f;
#pragma unroll
    for (int i = 0; i < 3; i++) {
        int k4 = t + 256 * i;
        float4 w = W4[k4];
        float4 x = x4[k4];
        sum += w.x * x.x + w.y * x.y + w.z * x.z + w.w * x.w;
    }
    __shared__ float sred[4];
    int lane = t & 63, wid = t >> 6;
    for (int o = 32; o > 0; o >>= 1) sum += __shfl_down(sum, o, 64);
    if (lane == 0) sred[wid] = sum;
    __syncthreads();
    if (t == 0) {
        float v = sred[0] + sred[1] + sred[2] + sred[3];
        ws[WS_X + r] = fmaxf(v + comb_b[r], 0.f);
    }
}

// ---------- K4..K7: fused GRU layer ----------
// grid 1024 x 384 (6 waves). Wave w<3: dot(inp, Wih[w*HID + j]); w>=3: dot(h, Whh[...]).
__global__ __launch_bounds__(384) void k_gru(const float* __restrict__ inp,
                                             const float* __restrict__ h,
                                             const float* __restrict__ Wih,
                                             const float* __restrict__ Whh,
                                             const float* __restrict__ bih,
                                             const float* __restrict__ bhh,
                                             float* __restrict__ h_out) {
    int j = blockIdx.x;
    int t = threadIdx.x;
    int wv = t >> 6, lane = t & 63;
    __shared__ float dots[6];
    const float* W;
    const float* x;
    if (wv < 3) { W = Wih + ((size_t)wv * HID + j) * HID; x = inp; }
    else        { W = Whh + ((size_t)(wv - 3) * HID + j) * HID; x = h; }
    const float4* W4 = (const float4*)W;
    const float4* x4 = (const float4*)x;
    float sum = 0.f;
#pragma unroll
    for (int i = 0; i < 4; i++) {
        float4 w = W4[lane + 64 * i];
        float4 xx = x4[lane + 64 * i];
        sum += w.x * xx.x + w.y * xx.y + w.z * xx.z + w.w * xx.w;
    }
    for (int o = 32; o > 0; o >>= 1) sum += __shfl_down(sum, o, 64);
    if (lane == 0) dots[wv] = sum;
    __syncthreads();
    if (t == 0) {
        float ir = dots[0] + bih[j];
        float iz = dots[1] + bih[HID + j];
        float in_ = dots[2] + bih[2 * HID + j];
        float hr = dots[3] + bhh[j];
        float hz = dots[4] + bhh[HID + j];
        float hn = dots[5] + bhh[2 * HID + j];
        float rg = 1.f / (1.f + expf(-(ir + hr)));
        float zg = 1.f / (1.f + expf(-(iz + hz)));
        float ng = tanhf(in_ + rg * hn);
        h_out[j] = (1.f - zg) * ng + zg * h[j];
    }
}

// ---------- K8: output projection ----------
// grid 16000 x 256 (4 waves), wave-per-row, dot over 1024.
__global__ __launch_bounds__(256) void k_logits(const float* __restrict__ h3,
                                                const float* __restrict__ out_W,
                                                const float* __restrict__ out_b,
                                                float* __restrict__ ws) {
    int wv = threadIdx.x >> 6, lane = threadIdx.x & 63;
    int row = blockIdx.x * 4 + wv;   // < 64000
    const float4* W4 = (const float4*)(out_W + (size_t)row * HID);
    const float4* x4 = (const float4*)h3;
    float sum = 0.f;
#pragma unroll
    for (int i = 0; i < 4; i++) {
        float4 w = W4[lane + 64 * i];
        float4 x = x4[lane + 64 * i];
        sum += w.x * x.x + w.y * x.y + w.z * x.z + w.w * x.w;
    }
    for (int o = 32; o > 0; o >>= 1) sum += __shfl_down(sum, o, 64);
    if (lane == 0) ws[WS_LOGITS + row] = sum + out_b[row];
}

// ---------- K9: per-span max + logsumexp ----------
// grid 2 x 1024.
__global__ __launch_bounds__(1024) void k_red(float* __restrict__ ws) {
    int s = blockIdx.x, t = threadIdx.x;
    int lane = t & 63, wid = t >> 6;
    const float* l = ws + WS_LOGITS + (size_t)s * VOCAB;
    __shared__ float sred[16];
    __shared__ float bcast;
    float m = -INFINITY;
    for (int i = t; i < VOCAB; i += 1024) m = fmaxf(m, l[i]);
    for (int o = 32; o > 0; o >>= 1) m = fmaxf(m, __shfl_down(m, o, 64));
    if (lane == 0) sred[wid] = m;
    __syncthreads();
    if (t == 0) {
        float v = -INFINITY;
        for (int k = 0; k < 16; k++) v = fmaxf(v, sred[k]);
        bcast = v;
    }
    __syncthreads();
    float gmax = bcast;
    __syncthreads();
    float sum = 0.f;
    for (int i = t; i < VOCAB; i += 1024) sum += expf(l[i] - gmax);
    for (int o = 32; o > 0; o >>= 1) sum += __shfl_down(sum, o, 64);
    if (lane == 0) sred[wid] = sum;
    __syncthreads();
    if (t == 0) {
        float v = 0.f;
        for (int k = 0; k < 16; k++) v += sred[k];
        ws[WS_RED + s] = gmax;
        ws[WS_RED + 2 + s] = logf(v);
    }
}

// ---------- K10: logp write ----------
__global__ __launch_bounds__(256) void k_logp(const float* __restrict__ ws,
                                              float* __restrict__ out) {
    int i = blockIdx.x * 256 + threadIdx.x;
    if (i < SPAN * VOCAB) {
        int s = i / VOCAB;
        out[OUT_LOGP + i] = ws[WS_LOGITS + i] - ws[WS_RED + s] - ws[WS_RED + 2 + s];
    }
}

extern "C" void kernel_launch(void* const* d_in, const int* in_sizes, int n_in,
                              void* d_out, int out_size, void* d_ws, size_t ws_size,
                              hipStream_t stream) {
    const int* ids = (const int*)d_in[0];
    const float* hidden = (const float*)d_in[1];       // (4,1,1024)
    const float* enc = (const float*)d_in[2];          // (128,1024)
    const float* embedding = (const float*)d_in[3];    // (32000,1024)
    const float* attn_W = (const float*)d_in[4];       // (128,3072)
    const float* attn_b = (const float*)d_in[5];
    const float* comb_W = (const float*)d_in[6];       // (1024,3072)
    const float* comb_b = (const float*)d_in[7];
    const float* gru_Wih = (const float*)d_in[8];      // (4,3072,1024)
    const float* gru_Whh = (const float*)d_in[9];
    const float* gru_bih = (const float*)d_in[10];     // (4,3072)
    const float* gru_bhh = (const float*)d_in[11];
    const float* out_W = (const float*)d_in[12];       // (64000,1024)
    const float* out_b = (const float*)d_in[13];
    float* out = (float*)d_out;
    float* ws = (float*)d_ws;

    // K1: scores + emb gather
    k_scores<<<136, 256, 0, stream>>>(ids, hidden, embedding, attn_W, attn_b, ws);
    // K2: softmax + attn_applied (+ attn_weights output)
    k_softmax_apply<<<8, 128, 0, stream>>>(enc, ws, out);
    // K3: comb + relu
    k_comb<<<1024, 256, 0, stream>>>(comb_W, comb_b, ws);
    // K4..K7: GRU layers
    for (int l = 0; l < LAYERS; l++) {
        const float* inp = (l == 0) ? (ws + WS_X) : (out + OUT_HID + (l - 1) * HID);
        k_gru<<<1024, 384, 0, stream>>>(inp,
                                        hidden + (size_t)l * HID,
                                        gru_Wih + (size_t)l * 3 * HID * HID,
                                        gru_Whh + (size_t)l * 3 * HID * HID,
                                        gru_bih + (size_t)l * 3 * HID,
                                        gru_bhh + (size_t)l * 3 * HID,
                                        out + OUT_HID + l * HID);
    }
    // K8: logits
    k_logits<<<16000, 256, 0, stream>>>(out + OUT_HID + 3 * HID, out_W, out_b, ws);
    // K9: per-span reductions
    k_red<<<2, 1024, 0, stream>>>(ws);
    // K10: logp
    k_logp<<<250, 256, 0, stream>>>(ws, out);
}

// Round 2
// 513.435 us; speedup vs baseline: 1.0078x; 1.0078x over previous
//
#include <hip/hip_runtime.h>
#include <math.h>

#define HID 1024
#define VOCAB 32000
#define LAYERS 4
#define MAXLEN 128
#define SPAN 2

// d_out layout (floats): logp [0,64000) | hidden_new [64000,68096) | attn_w [68096,68224)
#define OUT_LOGP 0
#define OUT_HID 64000
#define OUT_ATTNW 68096

// ws layout (floats)
#define WS_XCAT 0       // 3072: emb(2048) | attn_applied(1024)
#define WS_SCORES 3072  // 128
#define WS_X 3200       // 1024 (comb output)
#define WS_RED 4224     // 128: 64 chunk-partials x (max, sumexp)
#define WS_LOGITS 8192  // 64000

// ---------- K1: attention scores + emb gather ----------
// grid 136 x 256. Blocks 0..127: score[b] = dot(attn_in, attn_W[b]) + attn_b[b]
// Blocks 128..135: copy emb (2048 floats) into ws xcat.
__global__ __launch_bounds__(256) void k_scores(const int* __restrict__ ids,
                                                const float* __restrict__ hidden,
                                                const float* __restrict__ embedding,
                                                const float* __restrict__ attn_W,
                                                const float* __restrict__ attn_b,
                                                float* __restrict__ ws) {
    int b = blockIdx.x;
    int t = threadIdx.x;
    if (b < MAXLEN) {
        const float4* W4 = (const float4*)(attn_W + (size_t)b * 3072);
        float sum = 0.f;
#pragma unroll
        for (int i = 0; i < 3; i++) {
            int k4 = t + 256 * i;            // 0..767
            float4 w = W4[k4];
            int e = k4 * 4;                  // element index base
            float4 x;
            if (e < 2048) {
                int row = ids[e >> 10];
                x = *(const float4*)(embedding + (size_t)row * HID + (e & 1023));
            } else {
                x = *(const float4*)(hidden + (e - 2048));  // hidden[0]
            }
            sum += w.x * x.x + w.y * x.y + w.z * x.z + w.w * x.w;
        }
        __shared__ float sred[4];
        int lane = t & 63, wid = t >> 6;
        for (int o = 32; o > 0; o >>= 1) sum += __shfl_down(sum, o, 64);
        if (lane == 0) sred[wid] = sum;
        __syncthreads();
        if (t == 0) {
            float v = sred[0] + sred[1] + sred[2] + sred[3];
            ws[WS_SCORES + b] = v + attn_b[b];
        }
    } else {
        int idx = (b - MAXLEN) * 256 + t;    // 0..2047
        int row = ids[idx >> 10];
        ws[WS_XCAT + idx] = embedding[(size_t)row * HID + (idx & 1023)];
    }
}

// ---------- K2: softmax(128) + attn_applied ----------
// grid 8 x 128. Each block redundantly computes softmax, then 128 output cols.
__global__ __launch_bounds__(128) void k_softmax_apply(const float* __restrict__ enc,
                                                       float* __restrict__ ws,
                                                       float* __restrict__ out) {
    __shared__ float w[MAXLEN];
    __shared__ float red[2];
    int t = threadIdx.x;        // 0..127, two waves
    int lane = t & 63, wid = t >> 6;
    float s = ws[WS_SCORES + t];
    float m = s;
    for (int o = 32; o > 0; o >>= 1) m = fmaxf(m, __shfl_down(m, o, 64));
    if (lane == 0) red[wid] = m;
    __syncthreads();
    float gmax = fmaxf(red[0], red[1]);
    __syncthreads();
    float e = expf(s - gmax);
    float sum = e;
    for (int o = 32; o > 0; o >>= 1) sum += __shfl_down(sum, o, 64);
    if (lane == 0) red[wid] = sum;
    __syncthreads();
    float gsum = red[0] + red[1];
    float wt = e / gsum;
    w[t] = wt;
    if (blockIdx.x == 0) out[OUT_ATTNW + t] = wt;
    __syncthreads();
    int i = blockIdx.x * 128 + t;   // 0..1023
    float acc = 0.f;
#pragma unroll 16
    for (int k = 0; k < MAXLEN; k++) acc += w[k] * enc[(size_t)k * HID + i];
    ws[WS_XCAT + 2048 + i] = acc;
}

// ---------- K3: comb matvec + relu ----------
__global__ __launch_bounds__(256) void k_comb(const float* __restrict__ comb_W,
                                              const float* __restrict__ comb_b,
                                              float* __restrict__ ws) {
    int r = blockIdx.x, t = threadIdx.x;
    const float4* W4 = (const float4*)(comb_W + (size_t)r * 3072);
    const float4* x4 = (const float4*)(ws + WS_XCAT);
    float sum = 0.f;
#pragma unroll
    for (int i = 0; i < 3; i++) {
        int k4 = t + 256 * i;
        float4 w = W4[k4];
        float4 x = x4[k4];
        sum += w.x * x.x + w.y * x.y + w.z * x.z + w.w * x.w;
    }
    __shared__ float sred[4];
    int lane = t & 63, wid = t >> 6;
    for (int o = 32; o > 0; o >>= 1) sum += __shfl_down(sum, o, 64);
    if (lane == 0) sred[wid] = sum;
    __syncthreads();
    if (t == 0) {
        float v = sred[0] + sred[1] + sred[2] + sred[3];
        ws[WS_X + r] = fmaxf(v + comb_b[r], 0.f);
    }
}

// ---------- K4..K7: fused GRU layer ----------
// grid 1024 x 384 (6 waves). Wave w<3: dot(inp, Wih row); w>=3: dot(h, Whh row).
__global__ __launch_bounds__(384) void k_gru(const float* __restrict__ inp,
                                             const float* __restrict__ h,
                                             const float* __restrict__ Wih,
                                             const float* __restrict__ Whh,
                                             const float* __restrict__ bih,
                                             const float* __restrict__ bhh,
                                             float* __restrict__ h_out) {
    int j = blockIdx.x;
    int t = threadIdx.x;
    int wv = t >> 6, lane = t & 63;
    __shared__ float dots[6];
    const float* W;
    const float* x;
    if (wv < 3) { W = Wih + ((size_t)wv * HID + j) * HID; x = inp; }
    else        { W = Whh + ((size_t)(wv - 3) * HID + j) * HID; x = h; }
    const float4* W4 = (const float4*)W;
    const float4* x4 = (const float4*)x;
    float sum = 0.f;
#pragma unroll
    for (int i = 0; i < 4; i++) {
        float4 w = W4[lane + 64 * i];
        float4 xx = x4[lane + 64 * i];
        sum += w.x * xx.x + w.y * xx.y + w.z * xx.z + w.w * xx.w;
    }
    for (int o = 32; o > 0; o >>= 1) sum += __shfl_down(sum, o, 64);
    if (lane == 0) dots[wv] = sum;
    __syncthreads();
    if (t == 0) {
        float ir = dots[0] + bih[j];
        float iz = dots[1] + bih[HID + j];
        float in_ = dots[2] + bih[2 * HID + j];
        float hr = dots[3] + bhh[j];
        float hz = dots[4] + bhh[HID + j];
        float hn = dots[5] + bhh[2 * HID + j];
        float rg = 1.f / (1.f + expf(-(ir + hr)));
        float zg = 1.f / (1.f + expf(-(iz + hz)));
        float ng = tanhf(in_ + rg * hn);
        h_out[j] = (1.f - zg) * ng + zg * h[j];
    }
}

// ---------- K8: output projection ----------
// grid 4000 x 256 (4 waves), 4 rows per wave -> 16 W loads in flight.
__global__ __launch_bounds__(256) void k_logits(const float* __restrict__ h3,
                                                const float* __restrict__ out_W,
                                                const float* __restrict__ out_b,
                                                float* __restrict__ ws) {
    int wv = threadIdx.x >> 6, lane = threadIdx.x & 63;
    int r0 = (blockIdx.x * 4 + wv) * 4;   // rows r0..r0+3, < 64000
    const float4* x4 = (const float4*)h3;
    float4 xv[4];
#pragma unroll
    for (int i = 0; i < 4; i++) xv[i] = x4[lane + 64 * i];
    const float4* W4 = (const float4*)(out_W + (size_t)r0 * HID);
    float s[4] = {0.f, 0.f, 0.f, 0.f};
#pragma unroll
    for (int r = 0; r < 4; r++) {
#pragma unroll
        for (int i = 0; i < 4; i++) {
            float4 w = W4[r * 256 + lane + 64 * i];
            s[r] += w.x * xv[i].x + w.y * xv[i].y + w.z * xv[i].z + w.w * xv[i].w;
        }
    }
#pragma unroll
    for (int r = 0; r < 4; r++)
        for (int o = 32; o > 0; o >>= 1) s[r] += __shfl_down(s[r], o, 64);
    if (lane == 0) {
        float4 b = *(const float4*)(out_b + r0);
        float4 res = make_float4(s[0] + b.x, s[1] + b.y, s[2] + b.z, s[3] + b.w);
        *(float4*)(ws + WS_LOGITS + r0) = res;
    }
}

// ---------- K9: per-chunk partial max + sumexp ----------
// grid 64 x 256: block b -> span b>>5, chunk b&31 (1000 elements each).
__global__ __launch_bounds__(256) void k_red(float* __restrict__ ws) {
    int b = blockIdx.x, t = threadIdx.x;
    int span = b >> 5, chunk = b & 31;
    int lane = t & 63, wid = t >> 6;
    const float* l = ws + WS_LOGITS + (size_t)span * VOCAB + chunk * 1000;
    __shared__ float sred[4];
    float m = -INFINITY;
    for (int i = t; i < 1000; i += 256) m = fmaxf(m, l[i]);
    for (int o = 32; o > 0; o >>= 1) m = fmaxf(m, __shfl_down(m, o, 64));
    if (lane == 0) sred[wid] = m;
    __syncthreads();
    float gmax = fmaxf(fmaxf(sred[0], sred[1]), fmaxf(sred[2], sred[3]));
    __syncthreads();
    float sum = 0.f;
    for (int i = t; i < 1000; i += 256) sum += expf(l[i] - gmax);
    for (int o = 32; o > 0; o >>= 1) sum += __shfl_down(sum, o, 64);
    if (lane == 0) sred[wid] = sum;
    __syncthreads();
    if (t == 0) {
        ws[WS_RED + b * 2] = gmax;
        ws[WS_RED + b * 2 + 1] = sred[0] + sred[1] + sred[2] + sred[3];
    }
}

// ---------- K10: combine partials + logp write ----------
// grid 250 x 256; blocks never straddle spans (32000 = 125 * 256).
__global__ __launch_bounds__(256) void k_logp(const float* __restrict__ ws,
                                              float* __restrict__ out) {
    int t = threadIdx.x;
    int i = blockIdx.x * 256 + t;
    int span = blockIdx.x / 125;
    __shared__ float gm_s, ls_s;
    if (t < 64) {
        float m = -INFINITY, sm = 0.f;
        if (t < 32) {
            m = ws[WS_RED + (span * 32 + t) * 2];
            sm = ws[WS_RED + (span * 32 + t) * 2 + 1];
        }
        float gm = m;
        for (int o = 32; o > 0; o >>= 1) gm = fmaxf(gm, __shfl_down(gm, o, 64));
        gm = __shfl(gm, 0, 64);
        float e = sm * expf(m - gm);   // m=-INF, sm=0 -> 0
        for (int o = 32; o > 0; o >>= 1) e += __shfl_down(e, o, 64);
        if (t == 0) { gm_s = gm; ls_s = logf(e); }
    }
    __syncthreads();
    out[OUT_LOGP + i] = ws[WS_LOGITS + i] - gm_s - ls_s;
}

extern "C" void kernel_launch(void* const* d_in, const int* in_sizes, int n_in,
                              void* d_out, int out_size, void* d_ws, size_t ws_size,
                              hipStream_t stream) {
    const int* ids = (const int*)d_in[0];
    const float* hidden = (const float*)d_in[1];       // (4,1,1024)
    const float* enc = (const float*)d_in[2];          // (128,1024)
    const float* embedding = (const float*)d_in[3];    // (32000,1024)
    const float* attn_W = (const float*)d_in[4];       // (128,3072)
    const float* attn_b = (const float*)d_in[5];
    const float* comb_W = (const float*)d_in[6];       // (1024,3072)
    const float* comb_b = (const float*)d_in[7];
    const float* gru_Wih = (const float*)d_in[8];      // (4,3072,1024)
    const float* gru_Whh = (const float*)d_in[9];
    const float* gru_bih = (const float*)d_in[10];     // (4,3072)
    const float* gru_bhh = (const float*)d_in[11];
    const float* out_W = (const float*)d_in[12];       // (64000,1024)
    const float* out_b = (const float*)d_in[13];
    float* out = (float*)d_out;
    float* ws = (float*)d_ws;

    k_scores<<<136, 256, 0, stream>>>(ids, hidden, embedding, attn_W, attn_b, ws);
    k_softmax_apply<<<8, 128, 0, stream>>>(enc, ws, out);
    k_comb<<<1024, 256, 0, stream>>>(comb_W, comb_b, ws);
    for (int l = 0; l < LAYERS; l++) {
        const float* inp = (l == 0) ? (ws + WS_X) : (out + OUT_HID + (l - 1) * HID);
        k_gru<<<1024, 384, 0, stream>>>(inp,
                                        hidden + (size_t)l * HID,
                                        gru_Wih + (size_t)l * 3 * HID * HID,
                                        gru_Whh + (size_t)l * 3 * HID * HID,
                                        gru_bih + (size_t)l * 3 * HID,
                                        gru_bhh + (size_t)l * 3 * HID,
                                        out + OUT_HID + l * HID);
    }
    k_logits<<<4000, 256, 0, stream>>>(out + OUT_HID + 3 * HID, out_W, out_b, ws);
    k_red<<<64, 256, 0, stream>>>(ws);
    k_logp<<<250, 256, 0, stream>>>(ws, out);
}